// Round 3
// baseline (121.903 us; speedup 1.0000x reference)
//
#include <hip/hip_runtime.h>
#include <hip/hip_bf16.h>
#include <math.h>

#define NPIX 4096

typedef __attribute__((ext_vector_type(8))) short s8;    // 8 x bf16 (4 VGPRs)
typedef __attribute__((ext_vector_type(4))) short s4;    // 4 x bf16 (2 VGPRs)
typedef __attribute__((ext_vector_type(16))) float f16v; // 16 x f32 (32x32 acc)

static __device__ __forceinline__ unsigned packbf2(float a, float b) {
    union { __hip_bfloat162 h; unsigned u; } x;
    x.h = __float22bfloat162_rn(make_float2(a, b));
    return x.u;
}
static __device__ __forceinline__ float fexp2(float x) {
#if __has_builtin(__builtin_amdgcn_exp2f)
    return __builtin_amdgcn_exp2f(x);
#else
    return exp2f(x);
#endif
}

// ---------------------------------------------------------------------------
// Kernel 1: prep v2 — occupancy fix. Old: grid 256 = 1 blk/CU = 1 wave/SIMD,
// 27.6 us for ~6.5 MB + 34 MFLOP (pure latency). New: grid 512 x 512 thr =
// 16 waves/CU. Block (b, n-chunk, og): og=0 computes q (8 outputs), og=1
// computes k. Wave-group g (t>>6) owns output channel g: one 64-FMA dot per
// thread. xbf conversion split: og=0 writes c<32, og=1 writes c>=32.
// q/k stores transposed through LDS -> coalesced 16B-per-pixel rows.
// ---------------------------------------------------------------------------
__global__ __launch_bounds__(512) void prep_kernel(
    const float* __restrict__ x,
    const float* __restrict__ Wq, const float* __restrict__ bq,
    const float* __restrict__ Wk, const float* __restrict__ bk,
    __hip_bfloat16* __restrict__ qbf, __hip_bfloat16* __restrict__ kbf,
    __hip_bfloat16* __restrict__ xbf)
{
    __shared__ float Xp[64][65];
    __shared__ unsigned short Qs[64][8];
    int t = threadIdx.x;
    int p = t & 63;                  // pixel lane
    int g = t >> 6;                  // 0..7 = output channel (wave-uniform)
    int bid = blockIdx.x;
    int og = bid & 1;                // 0: q, 1: k
    int n0 = ((bid >> 1) & 63) << 6;
    int b  = bid >> 7;

    const float* xb = x + ((size_t)b << 18);
    __hip_bfloat16* xbb = xbf + ((size_t)b << 18);
#pragma unroll
    for (int u = 0; u < 8; ++u) {
        int c = g + (u << 3);
        float v = xb[((size_t)c << 12) + n0 + p];
        Xp[c][p] = v;
        if ((og == 0) ? (u < 4) : (u >= 4))   // split conversion halves
            xbb[((size_t)c << 12) + n0 + p] = __float2bfloat16(v);
    }
    __syncthreads();

    const float* W  = og ? Wk : Wq;
    const float* bb = og ? bk : bq;
    const float* wr = W + g * 64;            // wave-uniform row
    float acc = bb[g];
#pragma unroll
    for (int c = 0; c < 64; ++c) acc = fmaf(wr[c], Xp[c][p], acc);
    if (!og) acc *= 1.4426950408889634f;     // fold log2(e) into q

    union { __hip_bfloat16 h; unsigned short u; } cv;
    cv.h = __float2bfloat16(acc);
    Qs[p][g] = cv.u;
    __syncthreads();

    if (t < 64) {
        __hip_bfloat16* dst = (og ? kbf : qbf) + ((size_t)(b * NPIX + n0 + t) << 3);
        *(s8*)dst = *(const s8*)&Qs[t][0];   // coalesced 16B per pixel
    }
}

// ---------------------------------------------------------------------------
// Kernel 2: fused flash — main loop IDENTICAL to the proven 41.6us structure
// (incl. R2 conflict-free staging map). ONE structural change: j-split across
// 2 blocks (grid 1024 = b x 128 i-tiles x 2 j-halves) -> 4 blocks/CU =
// 8 waves/SIMD (was 4). R2 evidence: all pipes <30% busy, conflicts 0,
// HBM 4.6% => latency/barrier-bound; double the resident waves to fill
// stalls and halve per-block serial chain (8 tiles instead of 16).
// Epilogue writes unnormalized partials O[64][32] + l[32] to workspace;
// combine kernel finishes (plain exp2 -> partials add exactly).
// ---------------------------------------------------------------------------
__global__ __launch_bounds__(512, 4) void flash_fused_kernel(
    const __hip_bfloat16* __restrict__ qbf, const __hip_bfloat16* __restrict__ kbf,
    const __hip_bfloat16* __restrict__ xbf,
    float* __restrict__ opart, float* __restrict__ lpart)
{
    // main loop: Xs [64][260] shorts @0 = 33280 B
    // epilogue:  OshA [32][68] @0 | OshB @8704 | Lsh [8][32] @34176
    __shared__ __align__(16) char pool[35200];
    unsigned short* Xs = (unsigned short*)pool;

    int t = threadIdx.x;
    int w    = t >> 6;               // 0..7 = j-stripe
    int lane = t & 63;
    int l32  = lane & 31;
    int lh   = lane >> 5;

    int bid = blockIdx.x;
    int jh  = bid & 1;               // j-half: tiles [jh*8, jh*8+8)
    int i0  = ((bid >> 1) & 127) << 5;
    int b   = bid >> 8;
    int jbase = jh << 3;

    const s8 zero8 = {0, 0, 0, 0, 0, 0, 0, 0};

    // Q B-frag: B[k=lh*8+r -> d][n=l32 -> i=i0+l32]; lh=1 half zeroed (d<8)
    s8 qf;
    {
        s8 qv = *(const s8*)(qbf + ((size_t)(b * NPIX + i0 + l32) << 3));
        qf = (lh == 0) ? qv : zero8;
    }

    f16v acc[2];                      // acc[cm]: O[c=cm*32+row(r,lh)][i=l32]
    f16v zero16;
#pragma unroll
    for (int r = 0; r < 16; ++r) { acc[0][r] = 0.f; acc[1][r] = 0.f; zero16[r] = 0.f; }
    float lsum = 0.f;

    const __hip_bfloat16* kb = kbf + ((size_t)(b * NPIX) << 3);
    const unsigned short* xg = (const unsigned short*)xbf + ((size_t)b << 18);

    // staging: thread t -> row c = 8w + (t&7), seg = (t>>3)&7 (conflict-free)
    int c = (w << 3) + (t & 7), seg = (t >> 3) & 7;
    const unsigned short* xsrc = xg + ((size_t)c << 12) + seg * 32;
    int xdst = c * 260 + seg * 32;    // shorts

    // preload first tile of this j-half
    uint2 pv[8];
    s8 kf;
    {
        const unsigned short* p = xsrc + (jbase << 8);
#pragma unroll
        for (int u = 0; u < 8; ++u) pv[u] = *(const uint2*)(p + u * 4);
        kf = *(const s8*)(kb + ((size_t)((jbase << 8) + w * 32 + l32) << 3));
    }

    for (int lt = 0; lt < 8; ++lt) {
        __syncthreads();   // A: previous tile's P·x readers done with Xs

        // stage-write from prefetched regs (8 x uint2, 8B-aligned)
        {
            unsigned short* dstp = Xs + xdst;
#pragma unroll
            for (int u = 0; u < 8; ++u) *(uint2*)(dstp + u * 4) = pv[u];
        }

        // score (no Xs dependency): S^T[j=stripe row][i=l32]
        f16v sC = __builtin_amdgcn_mfma_f32_32x32x16_bf16(kf, qf, zero16, 0, 0, 0);
        float e[16];
#pragma unroll
        for (int r = 0; r < 16; ++r) e[r] = fexp2(sC[r]);
#pragma unroll
        for (int r = 0; r < 16; ++r) lsum += e[r];
        unsigned P2[8];
#pragma unroll
        for (int s = 0; s < 8; ++s) P2[s] = packbf2(e[2 * s], e[2 * s + 1]);

        __syncthreads();   // B: Xs ready

        // prefetch next tile of this half (wraps; in flight under P·x)
        {
            int jn = (jbase + ((lt + 1) & 7)) << 8;
            const unsigned short* p = xsrc + jn;
#pragma unroll
            for (int u = 0; u < 8; ++u) pv[u] = *(const uint2*)(p + u * 4);
            kf = *(const s8*)(kb + ((size_t)(jn + w * 32 + l32) << 3));
        }

        // P·x: O[c][i] += X[c][j-stripe] · P[j][i]
#if __has_builtin(__builtin_amdgcn_mfma_f32_32x32x8bf16_1k)
#pragma unroll
        for (int cm = 0; cm < 2; ++cm) {
            const unsigned short* xrow = Xs + (cm * 32 + l32) * 260 + w * 32 + lh * 4;
#pragma unroll
            for (int q = 0; q < 4; ++q) {
                s4 xf = *(const s4*)(xrow + q * 8);
                union { uint2 u; s4 v; } pu;
                pu.u.x = P2[2 * q]; pu.u.y = P2[2 * q + 1];
                acc[cm] = __builtin_amdgcn_mfma_f32_32x32x8bf16_1k(xf, pu.v, acc[cm], 0, 0, 0);
            }
        }
#else
        {
            unsigned X0 = __shfl_xor(P2[0], 32), X1 = __shfl_xor(P2[1], 32);
            unsigned X2 = __shfl_xor(P2[2], 32), X3 = __shfl_xor(P2[3], 32);
            unsigned X4 = __shfl_xor(P2[4], 32), X5 = __shfl_xor(P2[5], 32);
            unsigned X6 = __shfl_xor(P2[6], 32), X7 = __shfl_xor(P2[7], 32);
            union { uint4 u[2]; s8 v[2]; } bf;
            bf.u[0].x = lh ? X2 : P2[0]; bf.u[0].y = lh ? X3 : P2[1];
            bf.u[0].z = lh ? P2[2] : X0; bf.u[0].w = lh ? P2[3] : X1;
            bf.u[1].x = lh ? X6 : P2[4]; bf.u[1].y = lh ? X7 : P2[5];
            bf.u[1].z = lh ? P2[6] : X4; bf.u[1].w = lh ? P2[7] : X5;
#pragma unroll
            for (int cm = 0; cm < 2; ++cm) {
                const unsigned short* xrow = Xs + (cm * 32 + l32) * 260 + w * 32 + lh * 8;
#pragma unroll
                for (int q = 0; q < 2; ++q) {
                    union { uint2 u[2]; s8 v; } xu;
                    xu.u[0] = *(const uint2*)(xrow + q * 16);
                    xu.u[1] = *(const uint2*)(xrow + q * 16 + 4);
                    acc[cm] = __builtin_amdgcn_mfma_f32_32x32x16_bf16(xu.v, bf.v[q], acc[cm], 0, 0, 0);
                }
            }
        }
#endif
    }

    // ---------------- epilogue: write partials (block-local reduce) ----------
    float* OshA = (float*)pool;                  // [32 i][68]
    float* OshB = (float*)(pool + 8704);         // [32 i][68]
    float* Lsh  = (float*)(pool + 34176);        // [8][32] (no Xs overlap)

    lsum += __shfl_xor(lsum, 32);                // full 32-j stripe sum per i
    if (lh == 0) Lsh[w * 32 + l32] = lsum;

    // 2-tree stripe reduction: waves 0-3 -> OshA, waves 4-7 -> OshB
    float* Og = (w >> 2) ? OshB : OshA;
    for (int s = 0; s < 4; ++s) {
        __syncthreads();
        if ((w & 3) == s) {
#pragma unroll
            for (int cm = 0; cm < 2; ++cm)
#pragma unroll
                for (int r = 0; r < 16; ++r) {
                    int cc = cm * 32 + (r & 3) + 8 * (r >> 2) + 4 * lh;
                    float* p = Og + l32 * 68 + cc;
                    if (s == 0) *p = acc[cm][r];
                    else        *p += acc[cm][r];
                }
        }
    }
    __syncthreads();

    if (t < 32) {
        float lt2 = 0.f;
#pragma unroll
        for (int ww = 0; ww < 8; ++ww) lt2 += Lsh[ww * 32 + t];
        lpart[(size_t)bid * 32 + t] = lt2;
    }
    {
        float* Op = opart + (size_t)bid * 2048;
        int i = t >> 4, sg = t & 15;
        float4 oa = *(const float4*)(OshA + i * 68 + sg * 4);
        float4 ob = *(const float4*)(OshB + i * 68 + sg * 4);
        *(float4*)(Op + i * 64 + sg * 4) =
            make_float4(oa.x + ob.x, oa.y + ob.y, oa.z + ob.z, oa.w + ob.w);
    }
}

// ---------------------------------------------------------------------------
// Kernel 3: combine — sum the 2 j-half partials, normalize, Wv projection +
// bias + residual (exact move of the old flash epilogue projection).
// ---------------------------------------------------------------------------
__global__ __launch_bounds__(512) void combine_kernel(
    const float* __restrict__ opart, const float* __restrict__ lpart,
    const float* __restrict__ Wv, const float* __restrict__ bv,
    const float* __restrict__ x, const float* __restrict__ gamma,
    float* __restrict__ out)
{
    __shared__ float Osum[32 * 68];
    __shared__ float Linv[32];
    __shared__ float bvs[64];
    __shared__ float Wvs[64 * 64];

    int t = threadIdx.x;
    int cid = blockIdx.x;            // 0..511 = b x 128 i-tiles
    int b = cid >> 7, it = cid & 127, i0 = it << 5;
    int base = (b << 8) | (it << 1); // flash bid of jh=0 partner
    const float* p0 = opart + (size_t)base * 2048;
    const float* p1 = p0 + 2048;

    {
        int i = t >> 4, sg = t & 15;
        float4 a  = *(const float4*)(p0 + i * 64 + sg * 4);
        float4 c4 = *(const float4*)(p1 + i * 64 + sg * 4);
        *(float4*)(Osum + i * 68 + sg * 4) =
            make_float4(a.x + c4.x, a.y + c4.y, a.z + c4.z, a.w + c4.w);
    }
    if (t < 32) Linv[t] = 1.0f / (lpart[(size_t)base * 32 + t] + lpart[(size_t)base * 32 + 32 + t]);
    if (t < 64) bvs[t] = bv[t];
    {
        const float4* wsrc = (const float4*)Wv;
        float4* wdst = (float4*)Wvs;
        wdst[t] = wsrc[t];
        wdst[t + 512] = wsrc[t + 512];
    }
    __syncthreads();

    int i  = t & 31;
    int cg = t >> 5;
    float inv = Linv[i];
    float res[4] = {0.f, 0.f, 0.f, 0.f};
#pragma unroll 4
    for (int cb = 0; cb < 16; ++cb) {
        float4 o = *(const float4*)(Osum + i * 68 + cb * 4);
#pragma unroll
        for (int k = 0; k < 4; ++k) {
            const float4 wv4 = *(const float4*)(Wvs + (cg * 4 + k) * 64 + cb * 4);
            res[k] = fmaf(wv4.x, o.x, fmaf(wv4.y, o.y, fmaf(wv4.z, o.z, fmaf(wv4.w, o.w, res[k]))));
        }
    }
    float g = gamma[0];
    const float* xr = x + ((size_t)b << 18) + i0;
    float* outp = out + ((size_t)b << 18) + i0;
#pragma unroll
    for (int k = 0; k < 4; ++k) {
        int cch = cg * 4 + k;
        float attn = fmaf(res[k], inv, bvs[cch]);
        size_t off = ((size_t)cch << 12) + i;
        outp[off] = fmaf(g, attn, xr[off]);
    }
}

extern "C" void kernel_launch(void* const* d_in, const int* in_sizes, int n_in,
                              void* d_out, int out_size, void* d_ws, size_t ws_size,
                              hipStream_t stream) {
    const float* x     = (const float*)d_in[0];
    const float* Wq    = (const float*)d_in[1];
    const float* bq    = (const float*)d_in[2];
    const float* Wk    = (const float*)d_in[3];
    const float* bk    = (const float*)d_in[4];
    const float* Wv    = (const float*)d_in[5];
    const float* bv    = (const float*)d_in[6];
    const float* gamma = (const float*)d_in[7];
    float* out = (float*)d_out;

    // ws: qbf 256KB | kbf 256KB | xbf 2MB | opart 8MB | lpart 128KB
    __hip_bfloat16* qbf = (__hip_bfloat16*)d_ws;
    __hip_bfloat16* kbf = qbf + (size_t)4 * NPIX * 8;
    __hip_bfloat16* xbf = kbf + (size_t)4 * NPIX * 8;
    float* opart = (float*)(xbf + (size_t)4 * NPIX * 64);
    float* lpart = opart + (size_t)1024 * 2048;

    prep_kernel<<<512, 512, 0, stream>>>(x, Wq, bq, Wk, bk, qbf, kbf, xbf);
    flash_fused_kernel<<<1024, 512, 0, stream>>>(qbf, kbf, xbf, opart, lpart);
    combine_kernel<<<512, 512, 0, stream>>>(opart, lpart, Wv, bv, x, gamma, out);
}

// Round 4
// 113.762 us; speedup vs baseline: 1.0716x; 1.0716x over previous
//
#include <hip/hip_runtime.h>
#include <hip/hip_bf16.h>
#include <math.h>

#define NPIX 4096

typedef __attribute__((ext_vector_type(8))) short s8;    // 8 x bf16 (4 VGPRs)
typedef __attribute__((ext_vector_type(16))) float f16v; // 16 x f32 (32x32 acc)

static __device__ __forceinline__ unsigned packbf2(float a, float b) {
    union { __hip_bfloat162 h; unsigned u; } x;
    x.h = __float22bfloat162_rn(make_float2(a, b));
    return x.u;
}
static __device__ __forceinline__ float fexp2(float x) {
#if __has_builtin(__builtin_amdgcn_exp2f)
    return __builtin_amdgcn_exp2f(x);
#else
    return exp2f(x);
#endif
}

// Half-swap of two regs across the lane<32 / lane>=32 boundary:
//   x = {a.row0, b.row0}  (lanes<32 keep a; lanes>=32 get b's lanes 0..31)
//   y = {a.row1, b.row1}  (lanes<32 get a's lanes 32..63; lanes>=32 keep b)
static __device__ __forceinline__ void lane_swap(unsigned a, unsigned b, int lh,
                                                 unsigned &x, unsigned &y) {
#if __has_builtin(__builtin_amdgcn_permlane32_swap)
    auto r = __builtin_amdgcn_permlane32_swap((int)a, (int)b, false, false);
    x = (unsigned)r[0];
    y = (unsigned)r[1];
#else
    unsigned sa = __shfl_xor(a, 32), sb = __shfl_xor(b, 32);
    x = lh ? sb : a;
    y = lh ? b : sa;
#endif
}

// ---------------------------------------------------------------------------
// Kernel 1: prep v2 (R3, passed) — 512 blocks x 512 thr, og=0:q / og=1:k,
// one 64-FMA dot per thread, transposed store through LDS.
// ---------------------------------------------------------------------------
__global__ __launch_bounds__(512) void prep_kernel(
    const float* __restrict__ x,
    const float* __restrict__ Wq, const float* __restrict__ bq,
    const float* __restrict__ Wk, const float* __restrict__ bk,
    __hip_bfloat16* __restrict__ qbf, __hip_bfloat16* __restrict__ kbf,
    __hip_bfloat16* __restrict__ xbf)
{
    __shared__ float Xp[64][65];
    __shared__ unsigned short Qs[64][8];
    int t = threadIdx.x;
    int p = t & 63;                  // pixel lane
    int g = t >> 6;                  // 0..7 = output channel (wave-uniform)
    int bid = blockIdx.x;
    int og = bid & 1;                // 0: q, 1: k
    int n0 = ((bid >> 1) & 63) << 6;
    int b  = bid >> 7;

    const float* xb = x + ((size_t)b << 18);
    __hip_bfloat16* xbb = xbf + ((size_t)b << 18);
#pragma unroll
    for (int u = 0; u < 8; ++u) {
        int c = g + (u << 3);
        float v = xb[((size_t)c << 12) + n0 + p];
        Xp[c][p] = v;
        if ((og == 0) ? (u < 4) : (u >= 4))   // split conversion halves
            xbb[((size_t)c << 12) + n0 + p] = __float2bfloat16(v);
    }
    __syncthreads();

    const float* W  = og ? Wk : Wq;
    const float* bb = og ? bk : bq;
    const float* wr = W + g * 64;            // wave-uniform row
    float acc = bb[g];
#pragma unroll
    for (int c = 0; c < 64; ++c) acc = fmaf(wr[c], Xp[c][p], acc);
    if (!og) acc *= 1.4426950408889634f;     // fold log2(e) into q

    union { __hip_bfloat16 h; unsigned short u; } cv;
    cv.h = __float2bfloat16(acc);
    Qs[p][g] = cv.u;
    __syncthreads();

    if (t < 64) {
        __hip_bfloat16* dst = (og ? kbf : qbf) + ((size_t)(b * NPIX + n0 + t) << 3);
        *(s8*)dst = *(const s8*)&Qs[t][0];   // coalesced 16B per pixel
    }
}

// ---------------------------------------------------------------------------
// Kernel 2: fused flash — R2 structure (43.2us, 512 blocks, fused epilogue,
// conflict-free staging) with ONE change: PV at K=16.
//   old PV: 8x mfma_32x32x8bf16_1k. Measured via MfmaUtil back-calc: ~32
//   SIMD-cyc each (MfmaUtil 16.2% = 32 tiles x 2 waves x (8+8*32) exactly)
//   = 1/4 the FLOP rate of 32x32x16 (8 cyc).
//   new PV: 4x mfma_32x32x16_bf16; B-frags from P2 pairs via 4
//   permlane32_swap (construction proven in R1's passing run; re-derived).
//   Matrix cycles/tile-wave: 264 -> 40. LDS reads stay 2xb64 (stride-260
//   rows are 8B-aligned only; b64 phases conflict-free).
// R3 lesson: j-split gave 0% (register-capped at 2 blocks/CU either way) —
// reverted to 512 blocks + fused epilogue.
// ---------------------------------------------------------------------------
__global__ __launch_bounds__(512, 4) void flash_fused_kernel(
    const __hip_bfloat16* __restrict__ qbf, const __hip_bfloat16* __restrict__ kbf,
    const __hip_bfloat16* __restrict__ xbf,
    const float* __restrict__ Wv, const float* __restrict__ bv,
    const float* __restrict__ x, const float* __restrict__ gamma,
    float* __restrict__ out)
{
    // main loop: Xs [64][260] shorts @0 = 33280 B
    // epilogue:  OshA [32][68] @0 | OshB @8704 | Linv @17408 | bvs @17536 |
    //            Wvs @17792 (16384) | Lsh [8][32] @34176 (beyond Xs)
    __shared__ __align__(16) char pool[35200];
    unsigned short* Xs = (unsigned short*)pool;

    int t = threadIdx.x;
    int w    = t >> 6;               // 0..7 = j-stripe
    int lane = t & 63;
    int l32  = lane & 31;
    int lh   = lane >> 5;

    int b  = blockIdx.x >> 7;
    int i0 = (blockIdx.x & 127) << 5;

    const s8 zero8 = {0, 0, 0, 0, 0, 0, 0, 0};

    // Q B-frag: B[k=lh*8+r -> d][n=l32 -> i=i0+l32]; lh=1 half zeroed (d<8)
    s8 qf;
    {
        s8 qv = *(const s8*)(qbf + ((size_t)(b * NPIX + i0 + l32) << 3));
        qf = (lh == 0) ? qv : zero8;
    }

    f16v acc[2];                      // acc[cm]: O[c=cm*32+row(r,lh)][i=l32]
    f16v zero16;
#pragma unroll
    for (int r = 0; r < 16; ++r) { acc[0][r] = 0.f; acc[1][r] = 0.f; zero16[r] = 0.f; }
    float lsum = 0.f;

    const __hip_bfloat16* kb = kbf + ((size_t)(b * NPIX) << 3);
    const unsigned short* xg = (const unsigned short*)xbf + ((size_t)b << 18);

    // staging: thread t -> row c = 8w + (t&7), seg = (t>>3)&7 (conflict-free)
    int c = (w << 3) + (t & 7), seg = (t >> 3) & 7;
    const unsigned short* xsrc = xg + ((size_t)c << 12) + seg * 32;
    int xdst = c * 260 + seg * 32;    // shorts

    // preload tile 0
    uint2 pv[8];
    s8 kf;
    {
        const unsigned short* p = xsrc;
#pragma unroll
        for (int u = 0; u < 8; ++u) pv[u] = *(const uint2*)(p + u * 4);
        kf = *(const s8*)(kb + ((size_t)(w * 32 + l32) << 3));
    }

    for (int jt = 0; jt < 16; ++jt) {
        __syncthreads();   // A: previous tile's P·x readers done with Xs

        // stage-write from prefetched regs (8 x uint2, 8B-aligned)
        {
            unsigned short* dstp = Xs + xdst;
#pragma unroll
            for (int u = 0; u < 8; ++u) *(uint2*)(dstp + u * 4) = pv[u];
        }

        // score (no Xs dependency): S^T[j=stripe row][i=l32]
        f16v sC = __builtin_amdgcn_mfma_f32_32x32x16_bf16(kf, qf, zero16, 0, 0, 0);
        float e[16];
#pragma unroll
        for (int r = 0; r < 16; ++r) e[r] = fexp2(sC[r]);
#pragma unroll
        for (int r = 0; r < 16; ++r) lsum += e[r];
        unsigned P2[8];
#pragma unroll
        for (int s = 0; s < 8; ++s) P2[s] = packbf2(e[2 * s], e[2 * s + 1]);

        __syncthreads();   // B: Xs ready

        // prefetch next tile (wraps; in flight under P·x)
        {
            int jn = ((jt + 1) & 15) << 8;
            const unsigned short* p = xsrc + jn;
#pragma unroll
            for (int u = 0; u < 8; ++u) pv[u] = *(const uint2*)(p + u * 4);
            kf = *(const s8*)(kb + ((size_t)(jn + w * 32 + l32) << 3));
        }

        // build K=16 B-frags: bf0 = j_local 0..15, bf1 = 16..31.
        // P2[s] holds j pair {2(s&1)+8(s>>1)+4lh, +1} for i=l32.
        unsigned b00, b01, b02, b03, b10, b11, b12, b13;
        lane_swap(P2[0], P2[2], lh, b00, b02);
        lane_swap(P2[1], P2[3], lh, b01, b03);
        lane_swap(P2[4], P2[6], lh, b10, b12);
        lane_swap(P2[5], P2[7], lh, b11, b13);
        union { unsigned u[4]; s8 v; } bf0, bf1;
        bf0.u[0] = b00; bf0.u[1] = b01; bf0.u[2] = b02; bf0.u[3] = b03;
        bf1.u[0] = b10; bf1.u[1] = b11; bf1.u[2] = b12; bf1.u[3] = b13;

        // P·x: O[c][i] += X[c][j-stripe] · P[j][i], 2 K=16 MFMAs per cm
#pragma unroll
        for (int cm = 0; cm < 2; ++cm) {
            const unsigned short* xrow = Xs + (cm * 32 + l32) * 260 + w * 32 + lh * 8;
            union { uint2 u2[2]; s8 v; } xu0, xu1;
            xu0.u2[0] = *(const uint2*)(xrow);
            xu0.u2[1] = *(const uint2*)(xrow + 4);
            acc[cm] = __builtin_amdgcn_mfma_f32_32x32x16_bf16(xu0.v, bf0.v, acc[cm], 0, 0, 0);
            xu1.u2[0] = *(const uint2*)(xrow + 16);
            xu1.u2[1] = *(const uint2*)(xrow + 20);
            acc[cm] = __builtin_amdgcn_mfma_f32_32x32x16_bf16(xu1.v, bf1.v, acc[cm], 0, 0, 0);
        }
    }

    // ---------------- epilogue (block-local, no fences) ----------------
    float* OshA = (float*)pool;                  // [32 i][68]
    float* OshB = (float*)(pool + 8704);         // [32 i][68]
    float* Linv = (float*)(pool + 17408);        // [32]
    float* bvs  = (float*)(pool + 17536);        // [64]
    float* Wvs  = (float*)(pool + 17792);        // [64][64]
    float* Lsh  = (float*)(pool + 34176);        // [8][32] (no Xs overlap)

    lsum += __shfl_xor(lsum, 32);                // full 32-j stripe sum per i
    if (lh == 0) Lsh[w * 32 + l32] = lsum;

    // 2-tree stripe reduction: waves 0-3 -> OshA, waves 4-7 -> OshB
    float* Og = (w >> 2) ? OshB : OshA;
    for (int s = 0; s < 4; ++s) {
        __syncthreads();
        if ((w & 3) == s) {
#pragma unroll
            for (int cm = 0; cm < 2; ++cm)
#pragma unroll
                for (int r = 0; r < 16; ++r) {
                    int cc = cm * 32 + (r & 3) + 8 * (r >> 2) + 4 * lh;
                    float* p = Og + l32 * 68 + cc;
                    if (s == 0) *p = acc[cm][r];
                    else        *p += acc[cm][r];
                }
        }
    }
    __syncthreads();

    // stage Linv / bv / Wv
    if (t < 32) {
        float lt = 0.f;
#pragma unroll
        for (int ww = 0; ww < 8; ++ww) lt += Lsh[ww * 32 + t];
        Linv[t] = 1.0f / lt;
    }
    if (t < 64) bvs[t] = bv[t];
    {
        const float4* wsrc = (const float4*)Wv;
        float4* wdst = (float4*)Wvs;
        wdst[t] = wsrc[t];
        wdst[t + 512] = wsrc[t + 512];
    }
    __syncthreads();

    // projection + residual: i = t&31, cg = t>>5 (0..15) -> 4 channels each
    {
        int i  = t & 31;
        int cg = t >> 5;
        float inv = Linv[i];
        float res[4] = {0.f, 0.f, 0.f, 0.f};
#pragma unroll 4
        for (int cb = 0; cb < 16; ++cb) {
            float4 oa = *(const float4*)(OshA + i * 68 + cb * 4);
            float4 ob = *(const float4*)(OshB + i * 68 + cb * 4);
            float4 o = make_float4(oa.x + ob.x, oa.y + ob.y, oa.z + ob.z, oa.w + ob.w);
#pragma unroll
            for (int k = 0; k < 4; ++k) {
                const float4 wv4 = *(const float4*)(Wvs + (cg * 4 + k) * 64 + cb * 4);
                res[k] = fmaf(wv4.x, o.x, fmaf(wv4.y, o.y, fmaf(wv4.z, o.z, fmaf(wv4.w, o.w, res[k]))));
            }
        }
        float g = gamma[0];
        const float* xr = x + ((size_t)b << 18) + i0;
        float* outp = out + ((size_t)b << 18) + i0;
#pragma unroll
        for (int k = 0; k < 4; ++k) {
            int cch = cg * 4 + k;
            float attn = fmaf(res[k], inv, bvs[cch]);
            size_t off = ((size_t)cch << 12) + i;
            outp[off] = fmaf(g, attn, xr[off]);
        }
    }
}

extern "C" void kernel_launch(void* const* d_in, const int* in_sizes, int n_in,
                              void* d_out, int out_size, void* d_ws, size_t ws_size,
                              hipStream_t stream) {
    const float* x     = (const float*)d_in[0];
    const float* Wq    = (const float*)d_in[1];
    const float* bq    = (const float*)d_in[2];
    const float* Wk    = (const float*)d_in[3];
    const float* bk    = (const float*)d_in[4];
    const float* Wv    = (const float*)d_in[5];
    const float* bv    = (const float*)d_in[6];
    const float* gamma = (const float*)d_in[7];
    float* out = (float*)d_out;

    // ws: qbf 256KB | kbf 256KB | xbf 2MB
    __hip_bfloat16* qbf = (__hip_bfloat16*)d_ws;
    __hip_bfloat16* kbf = qbf + (size_t)4 * NPIX * 8;
    __hip_bfloat16* xbf = kbf + (size_t)4 * NPIX * 8;

    prep_kernel<<<512, 512, 0, stream>>>(x, Wq, bq, Wk, bk, qbf, kbf, xbf);
    flash_fused_kernel<<<512, 512, 0, stream>>>(qbf, kbf, xbf, Wv, bv, x, gamma, out);
}

// Round 5
// 101.222 us; speedup vs baseline: 1.2043x; 1.1239x over previous
//
#include <hip/hip_runtime.h>
#include <hip/hip_bf16.h>
#include <math.h>

#define NPIX 4096

typedef __attribute__((ext_vector_type(8))) short s8;    // 8 x bf16 (4 VGPRs)
typedef __attribute__((ext_vector_type(16))) float f16v; // 16 x f32 (32x32 acc)

typedef __attribute__((address_space(1))) const void glob_cv;
typedef __attribute__((address_space(3))) void lds_v;

static __device__ __forceinline__ unsigned packbf2(float a, float b) {
    union { __hip_bfloat162 h; unsigned u; } x;
    x.h = __float22bfloat162_rn(make_float2(a, b));
    return x.u;
}
static __device__ __forceinline__ float fexp2(float x) {
#if __has_builtin(__builtin_amdgcn_exp2f)
    return __builtin_amdgcn_exp2f(x);
#else
    return exp2f(x);
#endif
}

// async global->LDS 16B: HW writes lane l at (wave-uniform lds base) + l*16.
static __device__ __forceinline__ void gl_lds16(const unsigned short* g,
                                                unsigned short* l, int lane) {
#if __has_builtin(__builtin_amdgcn_global_load_lds)
    __builtin_amdgcn_global_load_lds((glob_cv*)g, (lds_v*)l, 16, 0, 0);
#else
    *(uint4*)(l + lane * 8) = *(const uint4*)g;   // correctness fallback
#endif
}

// Half-swap of two regs across the lane<32 / lane>=32 boundary.
static __device__ __forceinline__ void lane_swap(unsigned a, unsigned b, int lh,
                                                 unsigned &x, unsigned &y) {
#if __has_builtin(__builtin_amdgcn_permlane32_swap)
    auto r = __builtin_amdgcn_permlane32_swap((int)a, (int)b, false, false);
    x = (unsigned)r[0];
    y = (unsigned)r[1];
#else
    unsigned sa = __shfl_xor(a, 32), sb = __shfl_xor(b, 32);
    x = lh ? sb : a;
    y = lh ? b : sa;
#endif
}

// ---------------------------------------------------------------------------
// Kernel 1: prep v2 (unchanged from R4, passed).
// ---------------------------------------------------------------------------
__global__ __launch_bounds__(512) void prep_kernel(
    const float* __restrict__ x,
    const float* __restrict__ Wq, const float* __restrict__ bq,
    const float* __restrict__ Wk, const float* __restrict__ bk,
    __hip_bfloat16* __restrict__ qbf, __hip_bfloat16* __restrict__ kbf,
    __hip_bfloat16* __restrict__ xbf)
{
    __shared__ float Xp[64][65];
    __shared__ unsigned short Qs[64][8];
    int t = threadIdx.x;
    int p = t & 63;                  // pixel lane
    int g = t >> 6;                  // 0..7 = output channel (wave-uniform)
    int bid = blockIdx.x;
    int og = bid & 1;                // 0: q, 1: k
    int n0 = ((bid >> 1) & 63) << 6;
    int b  = bid >> 7;

    const float* xb = x + ((size_t)b << 18);
    __hip_bfloat16* xbb = xbf + ((size_t)b << 18);
#pragma unroll
    for (int u = 0; u < 8; ++u) {
        int c = g + (u << 3);
        float v = xb[((size_t)c << 12) + n0 + p];
        Xp[c][p] = v;
        if ((og == 0) ? (u < 4) : (u >= 4))   // split conversion halves
            xbb[((size_t)c << 12) + n0 + p] = __float2bfloat16(v);
    }
    __syncthreads();

    const float* W  = og ? Wk : Wq;
    const float* bb = og ? bk : bq;
    const float* wr = W + g * 64;            // wave-uniform row
    float acc = bb[g];
#pragma unroll
    for (int c = 0; c < 64; ++c) acc = fmaf(wr[c], Xp[c][p], acc);
    if (!og) acc *= 1.4426950408889634f;     // fold log2(e) into q

    union { __hip_bfloat16 h; unsigned short u; } cv;
    cv.h = __float2bfloat16(acc);
    Qs[p][g] = cv.u;
    __syncthreads();

    if (t < 64) {
        __hip_bfloat16* dst = (og ? kbf : qbf) + ((size_t)(b * NPIX + n0 + t) << 3);
        *(s8*)dst = *(const s8*)&Qs[t][0];   // coalesced 16B per pixel
    }
}

// ---------------------------------------------------------------------------
// Kernel 2: fused flash, R5 structure:
//  * staging via global_load_lds (16B) into double-buffered linear LDS
//    Xs[2][64 rows][256 shorts]; ONE __syncthreads per tile (its built-in
//    vmcnt(0) drain is the only wait — m97-proven pattern).
//  * LDS dest is forced-linear (DMA), so the bank swizzle moves to the
//    GLOBAL source: LDS granule (r, gl) holds global granule gl^(r&31)
//    (16B granules). Reads XOR the same involution -> 2-way b64 max (free).
//  * zero staging registers: R1's spill mode is structurally impossible.
//  * score / softmax / K=16 PV / epilogue: identical to R4 (passed).
// Evidence driving this: R2/R3/R4 showed all pipes <30% busy, 0 conflicts,
// HBM 4.6% -> serialized per-tile wait chain (2 barriers + lgkm/vmcnt
// drains) is the bottleneck. This halves the barrier count and removes the
// ds_write chain entirely.
// ---------------------------------------------------------------------------
__global__ __launch_bounds__(512, 4) void flash_fused_kernel(
    const __hip_bfloat16* __restrict__ qbf, const __hip_bfloat16* __restrict__ kbf,
    const __hip_bfloat16* __restrict__ xbf,
    const float* __restrict__ Wv, const float* __restrict__ bv,
    const float* __restrict__ x, const float* __restrict__ gamma,
    float* __restrict__ out)
{
    // main loop: Xs0 @0 (32768 B), Xs1 @32768 (32768 B), linear [64][512B]
    // epilogue (after final barrier, overlays): OshA @0 | OshB @8704 |
    //   Linv @17408 | bvs @17536 | Wvs @17792 (16384) | Lsh @34176
    __shared__ __align__(16) char pool[65536];
    unsigned short* Xs0 = (unsigned short*)pool;
    unsigned short* Xs1 = Xs0 + 16384;

    int t = threadIdx.x;
    int w    = t >> 6;               // 0..7 = j-stripe (wave-uniform)
    int lane = t & 63;
    int l32  = lane & 31;
    int lh   = lane >> 5;

    int b  = blockIdx.x >> 7;
    int i0 = (blockIdx.x & 127) << 5;

    const s8 zero8 = {0, 0, 0, 0, 0, 0, 0, 0};

    // Q B-frag: B[k=lh*8+r -> d][n=l32 -> i=i0+l32]; lh=1 half zeroed (d<8)
    s8 qf;
    {
        s8 qv = *(const s8*)(qbf + ((size_t)(b * NPIX + i0 + l32) << 3));
        qf = (lh == 0) ? qv : zero8;
    }

    f16v acc[2];                      // acc[cm]: O[c=cm*32+row(r,lh)][i=l32]
    f16v zero16;
#pragma unroll
    for (int r = 0; r < 16; ++r) { acc[0][r] = 0.f; acc[1][r] = 0.f; zero16[r] = 0.f; }
    float lsum = 0.f;

    const __hip_bfloat16* kb = kbf + ((size_t)(b * NPIX) << 3);
    const unsigned short* xg = (const unsigned short*)xbf + ((size_t)b << 18);

    // staging geometry: wave w owns rows 8w..8w+7. DMA u (0..3): lane l ->
    // row r = 8w+2u+(l>>5), LDS granule gl = l&31; global source pre-swizzled
    // to granule gl^(r&31) so LDS(r,gl) = global(r, gl^(r&31)).
    int rhalf = lane >> 5, gl = lane & 31;
    int offv[4];                      // shorts: r*4096 + swizzled granule
#pragma unroll
    for (int u = 0; u < 4; ++u) {
        int r = (w << 3) + (u << 1) + rhalf;
        offv[u] = (r << 12) + ((gl ^ (r & 31)) << 3);
    }
    // PV read offsets (shorts, loop-invariant): global granule 4w+lh (+2) of
    // row cr -> LDS granule (4w+lh)^(cr&31); cr&31 == l32 for both cm.
    int g1o = ((4 * w + lh) ^ l32) << 3;
    int g2o = ((4 * w + lh + 2) ^ l32) << 3;
    int woff = w * 32 + l32;          // kf source pixel within tile

#define STAGE(BUF, JT) do {                                                  \
        unsigned short* lb_ = (BUF) + (w << 11);                             \
        _Pragma("unroll")                                                    \
        for (int u_ = 0; u_ < 4; ++u_)                                       \
            gl_lds16(xg + offv[u_] + (JT) * 256, lb_ + (u_ << 9), lane);     \
    } while (0)

#define BODY(XSB, KF, JT) do {                                               \
        f16v sC = __builtin_amdgcn_mfma_f32_32x32x16_bf16(KF, qf, zero16, 0, 0, 0); \
        float e_[16];                                                        \
        _Pragma("unroll")                                                    \
        for (int r_ = 0; r_ < 16; ++r_) e_[r_] = fexp2(sC[r_]);              \
        _Pragma("unroll")                                                    \
        for (int r_ = 0; r_ < 16; ++r_) lsum += e_[r_];                      \
        unsigned P2[8];                                                      \
        _Pragma("unroll")                                                    \
        for (int s_ = 0; s_ < 8; ++s_) P2[s_] = packbf2(e_[2*s_], e_[2*s_+1]); \
        unsigned b00,b01,b02,b03,b10,b11,b12,b13;                            \
        lane_swap(P2[0], P2[2], lh, b00, b02);                               \
        lane_swap(P2[1], P2[3], lh, b01, b03);                               \
        lane_swap(P2[4], P2[6], lh, b10, b12);                               \
        lane_swap(P2[5], P2[7], lh, b11, b13);                               \
        union { unsigned u[4]; s8 v; } bf0, bf1;                             \
        bf0.u[0]=b00; bf0.u[1]=b01; bf0.u[2]=b02; bf0.u[3]=b03;              \
        bf1.u[0]=b10; bf1.u[1]=b11; bf1.u[2]=b12; bf1.u[3]=b13;              \
        _Pragma("unroll")                                                    \
        for (int cm_ = 0; cm_ < 2; ++cm_) {                                  \
            const unsigned short* xr_ = (XSB) + ((cm_ * 32 + l32) << 8);     \
            union { uint2 u2[2]; s8 v; } xu0, xu1;                           \
            xu0.u2[0] = *(const uint2*)(xr_ + g1o);                          \
            xu0.u2[1] = *(const uint2*)(xr_ + g1o + 4);                      \
            acc[cm_] = __builtin_amdgcn_mfma_f32_32x32x16_bf16(xu0.v, bf0.v, acc[cm_], 0, 0, 0); \
            xu1.u2[0] = *(const uint2*)(xr_ + g2o);                          \
            xu1.u2[1] = *(const uint2*)(xr_ + g2o + 4);                      \
            acc[cm_] = __builtin_amdgcn_mfma_f32_32x32x16_bf16(xu1.v, bf1.v, acc[cm_], 0, 0, 0); \
        }                                                                    \
        __syncthreads();  /* vmcnt(0)+lgkmcnt(0) drain: tile JT+1 landed,   \
                             all waves done reading XSB */                   \
        if ((JT) < 14) {                                                     \
            STAGE(XSB, (JT) + 2);                                            \
            KF = *(const s8*)(kb + ((size_t)(((JT) + 2) * 256 + woff) << 3)); \
        }                                                                    \
    } while (0)

    // prologue: tiles 0,1 -> buffers; k frags for tiles 0,1
    STAGE(Xs0, 0);
    STAGE(Xs1, 1);
    s8 kfA = *(const s8*)(kb + ((size_t)woff << 3));
    s8 kfB = *(const s8*)(kb + ((size_t)(256 + woff) << 3));
    __syncthreads();

    for (int jt = 0; jt < 16; jt += 2) {
        BODY(Xs0, kfA, jt);
        BODY(Xs1, kfB, jt + 1);
    }
#undef BODY
#undef STAGE

    // ---------------- epilogue (block-local, no fences) ----------------
    float* OshA = (float*)pool;                  // [32 i][68]
    float* OshB = (float*)(pool + 8704);         // [32 i][68]
    float* Linv = (float*)(pool + 17408);        // [32]
    float* bvs  = (float*)(pool + 17536);        // [64]
    float* Wvs  = (float*)(pool + 17792);        // [64][64]
    float* Lsh  = (float*)(pool + 34176);        // [8][32]

    lsum += __shfl_xor(lsum, 32);                // full 32-j stripe sum per i
    if (lh == 0) Lsh[w * 32 + l32] = lsum;       // after final barrier: safe

    // 2-tree stripe reduction: waves 0-3 -> OshA, waves 4-7 -> OshB
    float* Og = (w >> 2) ? OshB : OshA;
    for (int s = 0; s < 4; ++s) {
        __syncthreads();
        if ((w & 3) == s) {
#pragma unroll
            for (int cm = 0; cm < 2; ++cm)
#pragma unroll
                for (int r = 0; r < 16; ++r) {
                    int cc = cm * 32 + (r & 3) + 8 * (r >> 2) + 4 * lh;
                    float* p = Og + l32 * 68 + cc;
                    if (s == 0) *p = acc[cm][r];
                    else        *p += acc[cm][r];
                }
        }
    }
    __syncthreads();

    // stage Linv / bv / Wv
    if (t < 32) {
        float lt = 0.f;
#pragma unroll
        for (int ww = 0; ww < 8; ++ww) lt += Lsh[ww * 32 + t];
        Linv[t] = 1.0f / lt;
    }
    if (t < 64) bvs[t] = bv[t];
    {
        const float4* wsrc = (const float4*)Wv;
        float4* wdst = (float4*)Wvs;
        wdst[t] = wsrc[t];
        wdst[t + 512] = wsrc[t + 512];
    }
    __syncthreads();

    // projection + residual: i = t&31, cg = t>>5 (0..15) -> 4 channels each
    {
        int i  = t & 31;
        int cg = t >> 5;
        float inv = Linv[i];
        float res[4] = {0.f, 0.f, 0.f, 0.f};
#pragma unroll 4
        for (int cb = 0; cb < 16; ++cb) {
            float4 oa = *(const float4*)(OshA + i * 68 + cb * 4);
            float4 ob = *(const float4*)(OshB + i * 68 + cb * 4);
            float4 o = make_float4(oa.x + ob.x, oa.y + ob.y, oa.z + ob.z, oa.w + ob.w);
#pragma unroll
            for (int k = 0; k < 4; ++k) {
                const float4 wv4 = *(const float4*)(Wvs + (cg * 4 + k) * 64 + cb * 4);
                res[k] = fmaf(wv4.x, o.x, fmaf(wv4.y, o.y, fmaf(wv4.z, o.z, fmaf(wv4.w, o.w, res[k]))));
            }
        }
        float g = gamma[0];
        const float* xr = x + ((size_t)b << 18) + i0;
        float* outp = out + ((size_t)b << 18) + i0;
#pragma unroll
        for (int k = 0; k < 4; ++k) {
            int cch = cg * 4 + k;
            float attn = fmaf(res[k], inv, bvs[cch]);
            size_t off = ((size_t)cch << 12) + i;
            outp[off] = fmaf(g, attn, xr[off]);
        }
    }
}

extern "C" void kernel_launch(void* const* d_in, const int* in_sizes, int n_in,
                              void* d_out, int out_size, void* d_ws, size_t ws_size,
                              hipStream_t stream) {
    const float* x     = (const float*)d_in[0];
    const float* Wq    = (const float*)d_in[1];
    const float* bq    = (const float*)d_in[2];
    const float* Wk    = (const float*)d_in[3];
    const float* bk    = (const float*)d_in[4];
    const float* Wv    = (const float*)d_in[5];
    const float* bv    = (const float*)d_in[6];
    const float* gamma = (const float*)d_in[7];
    float* out = (float*)d_out;

    // ws: qbf 256KB | kbf 256KB | xbf 2MB
    __hip_bfloat16* qbf = (__hip_bfloat16*)d_ws;
    __hip_bfloat16* kbf = qbf + (size_t)4 * NPIX * 8;
    __hip_bfloat16* xbf = kbf + (size_t)4 * NPIX * 8;

    prep_kernel<<<512, 512, 0, stream>>>(x, Wq, bq, Wk, bk, qbf, kbf, xbf);
    flash_fused_kernel<<<512, 512, 0, stream>>>(qbf, kbf, xbf, Wv, bv, x, gamma, out);
}